// Round 4
// baseline (190.867 us; speedup 1.0000x reference)
//
#include <hip/hip_runtime.h>
#include <hip/hip_bf16.h>

#define NN 16384
#define DD 128
#define BM 256                 // rows per block
#define BCOLS 2048             // cols per block (one col-slice)
#define TILES 16               // BCOLS / 128
#define NBLOCKS 512            // 64 rstrips x 8 cslices
#define SQRT_SCALE 4.5398159622f   // sqrt(log2(e)/0.07); dot of scaled vecs == exp2 arg

typedef __attribute__((ext_vector_type(8))) short bf16x8;
typedef __attribute__((ext_vector_type(4))) float f32x4;

// ---------------- Kernel 1: fp32 -> scaled bf16, swizzled layout ---------------
// 16B chunk c of row r stored at chunk position (c ^ (r&15)); a linear
// global->LDS copy then yields a bank-conflict-free tile for ds_read_b128.
__global__ void convert_swz(const float* __restrict__ x, ushort* __restrict__ xb) {
    int t = blockIdx.x * blockDim.x + threadIdx.x;   // one thread per 8-elem chunk
    int r = t >> 4;
    int c = t & 15;
    const float4* src = (const float4*)(x + (size_t)r * DD + c * 8);
    float4 f0 = src[0];
    float4 f1 = src[1];
    float vals[8] = {f0.x, f0.y, f0.z, f0.w, f1.x, f1.y, f1.z, f1.w};
    bf16x8 v;
#pragma unroll
    for (int i = 0; i < 8; ++i) {
        __hip_bfloat16 h = __float2bfloat16(vals[i] * SQRT_SCALE);
        v[i] = (short)__builtin_bit_cast(unsigned short, h);
    }
    int cs = c ^ (r & 15);
    *(bf16x8*)(xb + (size_t)r * DD + cs * 8) = v;
}

// ---------------- Kernel 2: streaming X·X^T -> exp2 -> register row-sums -------
// Block = 256 rows x 2048 cols. 8 waves (4 row x 2 col), wave tile 64x64.
// A in registers for the whole kernel; B tiles double-buffered in LDS via
// global_load_lds + counted vmcnt. Row sums live in registers; one cross-lane
// reduce + LDS cw-pair combine at the end. No atomics.
__global__ __launch_bounds__(512, 4) void gemm_exp_stream(const ushort* __restrict__ xb,
                                                          float* __restrict__ rowsumP) {
    __shared__ __align__(16) ushort lB[2][128 * DD];   // 2 x 32 KB
    __shared__ float xch[4][64];                       // cw-pair combine

    const int tid  = threadIdx.x;
    const int lane = tid & 63;
    const int wid  = tid >> 6;       // 0..7
    const int frow = lane & 15;
    const int kq   = lane >> 4;

    // XCD locality: all blocks on one XCD share one 512 KB B-slab (L2-resident).
    const int bid    = blockIdx.x;
    const int cslice = bid & 7;
    const int rstrip = bid >> 3;     // 0..63
    const int rw = wid >> 1;         // 0..3
    const int cw = wid & 1;          // 0..1
    const int R0 = rstrip * BM;
    const int C0 = cslice * BCOLS;

    auto stage = [&](int buf, int t) {
        const char* g = (const char*)(xb + (size_t)(C0 + t * 128) * DD);
#pragma unroll
        for (int i = 0; i < 4; ++i) {
            int off = (wid * 4 + i) * 1024;
            __builtin_amdgcn_global_load_lds(
                (const __attribute__((address_space(1))) unsigned int*)(g + off + lane * 16),
                (__attribute__((address_space(3))) unsigned int*)((char*)&lB[buf][0] + off),
                16, 0, 0);
        }
    };

    stage(0, 0);

    // ---- A fragments: 64 rows per wave, full K=128, in registers forever ----
    bf16x8 af[4][4];                 // [m][kk]
#pragma unroll
    for (int m = 0; m < 4; ++m)
#pragma unroll
        for (int kk = 0; kk < 4; ++kk) {
            int ra = R0 + rw * 64 + m * 16 + frow;   // ra & 15 == frow
            int slot = (kk * 4 + kq) ^ frow;
            af[m][kk] = *(const bf16x8*)(xb + (size_t)ra * DD + slot * 8);
        }

    // ---- precomputed LDS byte offsets for B-fragment reads ----
    int boff[4][4];
#pragma unroll
    for (int n = 0; n < 4; ++n)
#pragma unroll
        for (int kk = 0; kk < 4; ++kk) {
            int rb = cw * 64 + n * 16 + frow;        // rb & 15 == frow
            int slot = (kk * 4 + kq) ^ frow;
            boff[n][kk] = rb * 256 + slot * 16;
        }

    const f32x4 zacc = {0.f, 0.f, 0.f, 0.f};
    float rs[4][4] = {};

    for (int t = 0; t < TILES; ++t) {
        const int cur = t & 1;
        if (t < TILES - 1) {
            stage(cur ^ 1, t + 1);
            asm volatile("s_waitcnt vmcnt(4)" ::: "memory");  // tile t (+A at t=0) landed
        } else {
            asm volatile("s_waitcnt vmcnt(0)" ::: "memory");
        }
        __builtin_amdgcn_s_barrier();

        const char* Bb = (const char*)&lB[cur][0];
        f32x4 acc[4][4];
#pragma unroll
        for (int kk = 0; kk < 4; ++kk) {
            bf16x8 bfr[4];
#pragma unroll
            for (int n = 0; n < 4; ++n)
                bfr[n] = *(const bf16x8*)(Bb + boff[n][kk]);
            __builtin_amdgcn_s_setprio(1);
            if (kk == 0) {
#pragma unroll
                for (int m = 0; m < 4; ++m)
#pragma unroll
                    for (int n = 0; n < 4; ++n)
                        acc[m][n] = __builtin_amdgcn_mfma_f32_16x16x32_bf16(
                            af[m][0], bfr[n], zacc, 0, 0, 0);
            } else {
#pragma unroll
                for (int m = 0; m < 4; ++m)
#pragma unroll
                    for (int n = 0; n < 4; ++n)
                        acc[m][n] = __builtin_amdgcn_mfma_f32_16x16x32_bf16(
                            af[m][kk], bfr[n], acc[m][n], 0, 0, 0);
            }
            __builtin_amdgcn_s_setprio(0);
        }
        __builtin_amdgcn_s_barrier();   // all reads of lB[cur] consumed

        // Register-only epilogue; acc is already the exp2 argument.
#pragma unroll
        for (int m = 0; m < 4; ++m)
#pragma unroll
            for (int j = 0; j < 4; ++j) {
                float s = (__builtin_amdgcn_exp2f(acc[m][0][j]) +
                           __builtin_amdgcn_exp2f(acc[m][1][j])) +
                          (__builtin_amdgcn_exp2f(acc[m][2][j]) +
                           __builtin_amdgcn_exp2f(acc[m][3][j]));
                rs[m][j] += s;
            }
    }

    // ---- cross-lane reduce over the 16 col-lanes ----
#pragma unroll
    for (int m = 0; m < 4; ++m)
#pragma unroll
        for (int j = 0; j < 4; ++j) {
            float s = rs[m][j];
            s += __shfl_xor(s, 1);
            s += __shfl_xor(s, 2);
            s += __shfl_xor(s, 4);
            s += __shfl_xor(s, 8);
            rs[m][j] = s;
        }

    // ---- combine the cw pair via LDS, store one partial per cslice ----
    if (frow == 0 && cw == 1) {
#pragma unroll
        for (int m = 0; m < 4; ++m)
#pragma unroll
            for (int j = 0; j < 4; ++j)
                xch[rw][m * 16 + kq * 4 + j] = rs[m][j];
    }
    __syncthreads();
    if (frow == 0 && cw == 0) {
        float* dst = rowsumP + (size_t)cslice * NN + R0 + rw * 64 + kq * 4;
#pragma unroll
        for (int m = 0; m < 4; ++m) {
            float4 v = {rs[m][0] + xch[rw][m * 16 + kq * 4 + 0],
                        rs[m][1] + xch[rw][m * 16 + kq * 4 + 1],
                        rs[m][2] + xch[rw][m * 16 + kq * 4 + 2],
                        rs[m][3] + xch[rw][m * 16 + kq * 4 + 3]};
            *(float4*)(dst + m * 16) = v;
        }
    }
}

// ---------------- Kernel 3a: per-row log, 64-block partial sums ----------------
__global__ void finalize_part(const float* __restrict__ rowsumP,
                              float* __restrict__ partial) {
    const int tid = threadIdx.x;
    const int r = blockIdx.x * 256 + tid;
    float rsum = 0.f;
#pragma unroll
    for (int p = 0; p < 8; ++p)
        rsum += rowsumP[p * NN + r];
    float s = __builtin_amdgcn_logf(rsum) * 0.69314718056f;
#pragma unroll
    for (int o = 1; o < 64; o <<= 1)
        s += __shfl_xor(s, o);
    __shared__ float wsum[4];
    if ((tid & 63) == 0) wsum[tid >> 6] = s;
    __syncthreads();
    if (tid == 0)
        partial[blockIdx.x] = wsum[0] + wsum[1] + wsum[2] + wsum[3];
}

// ---------------- Kernel 3b: final sum -----------------------------------------
__global__ void finalize_sum(const float* __restrict__ partial, float* __restrict__ out) {
    float s = partial[threadIdx.x];   // 64 threads
#pragma unroll
    for (int o = 1; o < 64; o <<= 1)
        s += __shfl_xor(s, o);
    if (threadIdx.x == 0)
        out[0] = s * (1.0f / NN);
}

extern "C" void kernel_launch(void* const* d_in, const int* in_sizes, int n_in,
                              void* d_out, int out_size, void* d_ws, size_t ws_size,
                              hipStream_t stream) {
    const float* x = (const float*)d_in[0];
    float* out = (float*)d_out;

    ushort* xb     = (ushort*)d_ws;                                // 4 MB scaled bf16
    float* rowsumP = (float*)((char*)d_ws + (size_t)NN * DD * 2);  // 8 x 64 KB partials
    float* partial = rowsumP + 8 * NN;                             // 64 floats

    convert_swz<<<(NN * 16) / 256, 256, 0, stream>>>(x, xb);
    gemm_exp_stream<<<NBLOCKS, 512, 0, stream>>>(xb, rowsumP);
    finalize_part<<<64, 256, 0, stream>>>(rowsumP, partial);
    finalize_sum<<<1, 64, 0, stream>>>(partial, out);
}

// Round 5
// 83.074 us; speedup vs baseline: 2.2976x; 2.2976x over previous
//
#include <hip/hip_runtime.h>
#include <hip/hip_bf16.h>

#define NN 16384
#define DD 128
#define BM 128                 // rows per block
#define BCOLS 4096             // cols per block (one col-quarter)
#define TILES 32               // BCOLS / 128
#define NBLOCKS 512            // 128 rstrips x 4 col-quarters
#define SQRT_SCALE 4.5398159622f   // sqrt(log2(e)/0.07); dot of scaled vecs == exp2 arg

typedef __attribute__((ext_vector_type(8))) short bf16x8;
typedef __attribute__((ext_vector_type(4))) float f32x4;

// ---------------- Kernel 1: fp32 -> scaled bf16, swizzled layout ---------------
// 16B chunk c of row r stored at chunk position (c ^ (r&15)); a linear
// global->LDS copy then yields a bank-conflict-free tile for ds_read_b128.
__global__ void convert_swz(const float* __restrict__ x, ushort* __restrict__ xb) {
    int t = blockIdx.x * blockDim.x + threadIdx.x;   // one thread per 8-elem chunk
    int r = t >> 4;
    int c = t & 15;
    const float4* src = (const float4*)(x + (size_t)r * DD + c * 8);
    float4 f0 = src[0];
    float4 f1 = src[1];
    float vals[8] = {f0.x, f0.y, f0.z, f0.w, f1.x, f1.y, f1.z, f1.w};
    bf16x8 v;
#pragma unroll
    for (int i = 0; i < 8; ++i) {
        __hip_bfloat16 h = __float2bfloat16(vals[i] * SQRT_SCALE);
        v[i] = (short)__builtin_bit_cast(unsigned short, h);
    }
    int cs = c ^ (r & 15);
    *(bf16x8*)(xb + (size_t)r * DD + cs * 8) = v;
}

// ---------------- Kernel 2: streaming X·X^T -> exp2 -> register row-sums -------
// Block = 128 rows x 4096 cols, 512 threads = 8 waves (4 row x 2 col), wave
// tile 32x64 (small on purpose: ~115 VGPR -> 4 waves/EU with 2 blocks/CU).
// A in registers; B tiles double-buffered in LDS via global_load_lds +
// counted vmcnt. Row sums in registers; single reduce at the end. No atomics.
__global__ __launch_bounds__(512, 4) void gemm_exp_stream(const ushort* __restrict__ xb,
                                                          float* __restrict__ rowsumP) {
    __shared__ __align__(16) ushort lB[2][128 * DD];   // 2 x 32 KB
    __shared__ float xch[4][32];                       // cw-pair combine

    const int tid  = threadIdx.x;
    const int lane = tid & 63;
    const int wid  = tid >> 6;       // 0..7
    const int frow = lane & 15;
    const int kq   = lane >> 4;

    // XCD locality: 2 XCDs share one 1 MB B-slab; per-XCD set ~3 MB < 4 MB L2.
    const int bid    = blockIdx.x;
    const int cq     = (bid & 7) >> 1;                 // 0..3
    const int rstrip = ((bid >> 3) << 1) | (bid & 1);  // 0..127, bijective
    const int rw = wid >> 1;         // 0..3 -> 32-row slice
    const int cw = wid & 1;          // 0..1 -> 64-col slice
    const int R0 = rstrip * BM;
    const int C0 = cq * BCOLS;

    auto stage = [&](int buf, int t) {
        const char* g = (const char*)(xb + (size_t)(C0 + t * 128) * DD);
#pragma unroll
        for (int i = 0; i < 4; ++i) {
            int off = (wid * 4 + i) * 1024;
            __builtin_amdgcn_global_load_lds(
                (const __attribute__((address_space(1))) unsigned int*)(g + off + lane * 16),
                (__attribute__((address_space(3))) unsigned int*)((char*)&lB[buf][0] + off),
                16, 0, 0);
        }
    };

    stage(0, 0);

    // ---- A fragments: 32 rows per wave, full K=128, in registers forever ----
    bf16x8 af[2][4];                 // [m][kk]  (32 VGPR)
#pragma unroll
    for (int m = 0; m < 2; ++m)
#pragma unroll
        for (int kk = 0; kk < 4; ++kk) {
            int ra = R0 + rw * 32 + m * 16 + frow;   // ra & 15 == frow
            int slot = (kk * 4 + kq) ^ frow;
            af[m][kk] = *(const bf16x8*)(xb + (size_t)ra * DD + slot * 8);
        }

    // ---- LDS byte offsets, decomposed to save VGPRs (4+4 instead of 16) ----
    int nbase[4], kkoff[4];
#pragma unroll
    for (int n = 0; n < 4; ++n)
        nbase[n] = (cw * 64 + n * 16 + frow) * 256 + ((kq ^ (frow & 3)) << 4);
#pragma unroll
    for (int kk = 0; kk < 4; ++kk)
        kkoff[kk] = (((kk << 2) ^ (frow & 12)) << 4);

    const f32x4 zacc = {0.f, 0.f, 0.f, 0.f};
    float rs[2][4] = {};

    for (int t = 0; t < TILES; ++t) {
        const int cur = t & 1;
        if (t < TILES - 1) {
            stage(cur ^ 1, t + 1);
            asm volatile("s_waitcnt vmcnt(4)" ::: "memory");  // tile t (+A at t=0) landed
        } else {
            asm volatile("s_waitcnt vmcnt(0)" ::: "memory");
        }
        __builtin_amdgcn_s_barrier();

        const char* Bb = (const char*)&lB[cur][0];
        f32x4 acc[2][4];
#pragma unroll
        for (int kk = 0; kk < 4; ++kk) {
            bf16x8 bfr[4];
#pragma unroll
            for (int n = 0; n < 4; ++n)
                bfr[n] = *(const bf16x8*)(Bb + nbase[n] + kkoff[kk]);
            __builtin_amdgcn_s_setprio(1);
            if (kk == 0) {
#pragma unroll
                for (int m = 0; m < 2; ++m)
#pragma unroll
                    for (int n = 0; n < 4; ++n)
                        acc[m][n] = __builtin_amdgcn_mfma_f32_16x16x32_bf16(
                            af[m][0], bfr[n], zacc, 0, 0, 0);
            } else {
#pragma unroll
                for (int m = 0; m < 2; ++m)
#pragma unroll
                    for (int n = 0; n < 4; ++n)
                        acc[m][n] = __builtin_amdgcn_mfma_f32_16x16x32_bf16(
                            af[m][kk], bfr[n], acc[m][n], 0, 0, 0);
            }
            __builtin_amdgcn_s_setprio(0);
        }
        __builtin_amdgcn_s_barrier();   // all reads of lB[cur] consumed

        // Register-only epilogue; acc is already the exp2 argument.
#pragma unroll
        for (int m = 0; m < 2; ++m)
#pragma unroll
            for (int j = 0; j < 4; ++j) {
                float s = (__builtin_amdgcn_exp2f(acc[m][0][j]) +
                           __builtin_amdgcn_exp2f(acc[m][1][j])) +
                          (__builtin_amdgcn_exp2f(acc[m][2][j]) +
                           __builtin_amdgcn_exp2f(acc[m][3][j]));
                rs[m][j] += s;
            }
    }

    // ---- cross-lane reduce over the 16 col-lanes ----
#pragma unroll
    for (int m = 0; m < 2; ++m)
#pragma unroll
        for (int j = 0; j < 4; ++j) {
            float s = rs[m][j];
            s += __shfl_xor(s, 1);
            s += __shfl_xor(s, 2);
            s += __shfl_xor(s, 4);
            s += __shfl_xor(s, 8);
            rs[m][j] = s;
        }

    // ---- combine the cw pair via LDS, store one partial per col-quarter ----
    if (frow == 0 && cw == 1) {
#pragma unroll
        for (int m = 0; m < 2; ++m)
#pragma unroll
            for (int j = 0; j < 4; ++j)
                xch[rw][m * 16 + kq * 4 + j] = rs[m][j];
    }
    __syncthreads();
    if (frow == 0 && cw == 0) {
        float* dst = rowsumP + (size_t)cq * NN + R0 + rw * 32 + kq * 4;
#pragma unroll
        for (int m = 0; m < 2; ++m) {
            float4 v = {rs[m][0] + xch[rw][m * 16 + kq * 4 + 0],
                        rs[m][1] + xch[rw][m * 16 + kq * 4 + 1],
                        rs[m][2] + xch[rw][m * 16 + kq * 4 + 2],
                        rs[m][3] + xch[rw][m * 16 + kq * 4 + 3]};
            *(float4*)(dst + m * 16) = v;
        }
    }
}

// ---------------- Kernel 3a: per-row log, 64-block partial sums ----------------
__global__ void finalize_part(const float* __restrict__ rowsumP,
                              float* __restrict__ partial) {
    const int tid = threadIdx.x;
    const int r = blockIdx.x * 256 + tid;
    float rsum = 0.f;
#pragma unroll
    for (int p = 0; p < 4; ++p)
        rsum += rowsumP[p * NN + r];
    float s = __builtin_amdgcn_logf(rsum) * 0.69314718056f;
#pragma unroll
    for (int o = 1; o < 64; o <<= 1)
        s += __shfl_xor(s, o);
    __shared__ float wsum[4];
    if ((tid & 63) == 0) wsum[tid >> 6] = s;
    __syncthreads();
    if (tid == 0)
        partial[blockIdx.x] = wsum[0] + wsum[1] + wsum[2] + wsum[3];
}

// ---------------- Kernel 3b: final sum -----------------------------------------
__global__ void finalize_sum(const float* __restrict__ partial, float* __restrict__ out) {
    float s = partial[threadIdx.x];   // 64 threads
#pragma unroll
    for (int o = 1; o < 64; o <<= 1)
        s += __shfl_xor(s, o);
    if (threadIdx.x == 0)
        out[0] = s * (1.0f / NN);
}

extern "C" void kernel_launch(void* const* d_in, const int* in_sizes, int n_in,
                              void* d_out, int out_size, void* d_ws, size_t ws_size,
                              hipStream_t stream) {
    const float* x = (const float*)d_in[0];
    float* out = (float*)d_out;

    ushort* xb     = (ushort*)d_ws;                                // 4 MB scaled bf16
    float* rowsumP = (float*)((char*)d_ws + (size_t)NN * DD * 2);  // 4 x 64 KB partials
    float* partial = rowsumP + 4 * NN;                             // 64 floats

    convert_swz<<<(NN * 16) / 256, 256, 0, stream>>>(x, xb);
    gemm_exp_stream<<<NBLOCKS, 512, 0, stream>>>(xb, rowsumP);
    finalize_part<<<64, 256, 0, stream>>>(rowsumP, partial);
    finalize_sum<<<1, 64, 0, stream>>>(partial, out);
}

// Round 6
// 81.221 us; speedup vs baseline: 2.3500x; 1.0228x over previous
//
#include <hip/hip_runtime.h>
#include <hip/hip_bf16.h>

#define NN 16384
#define DD 128
#define BM 128                 // rows per block (2 rowbands of 64)
#define BCOLS 4096             // cols per block (one col-quarter)
#define TCOLS 64               // cols per LDS tile
#define TILES 64               // BCOLS / TCOLS
#define NBLOCKS 512            // 128 rstrips x 4 col-quarters
#define SQRT_SCALE 4.5398159622f   // sqrt(log2(e)/0.07); dot of scaled vecs == exp2 arg

typedef __attribute__((ext_vector_type(8))) short bf16x8;
typedef __attribute__((ext_vector_type(4))) float f32x4;

// ---------------- Kernel 1: fp32 -> scaled bf16, swizzled layout ---------------
// 16B chunk c of row r stored at chunk position (c ^ (r&15)); a linear
// global->LDS copy then yields a bank-conflict-free tile for ds_read_b128.
__global__ void convert_swz(const float* __restrict__ x, ushort* __restrict__ xb) {
    int t = blockIdx.x * blockDim.x + threadIdx.x;   // one thread per 8-elem chunk
    int r = t >> 4;
    int c = t & 15;
    const float4* src = (const float4*)(x + (size_t)r * DD + c * 8);
    float4 f0 = src[0];
    float4 f1 = src[1];
    float vals[8] = {f0.x, f0.y, f0.z, f0.w, f1.x, f1.y, f1.z, f1.w};
    bf16x8 v;
#pragma unroll
    for (int i = 0; i < 8; ++i) {
        __hip_bfloat16 h = __float2bfloat16(vals[i] * SQRT_SCALE);
        v[i] = (short)__builtin_bit_cast(unsigned short, h);
    }
    int cs = c ^ (r & 15);
    *(bf16x8*)(xb + (size_t)r * DD + cs * 8) = v;
}

// ---------------- Kernel 2: streaming X·X^T -> exp2 -> register row-sums -------
// Block = 128 rows x 4096 cols, 512 threads = 8 waves (2 rowbands x 4 colwaves).
// Wave tile = 64 rows x 16 cols: af[4][4]=64 VGPR, acc[4]=16, rs=16 -> ~120 VGPR
// => 4 waves/SIMD AND only 2 LDS reads of each B element (R=64 halves LDS
// traffic vs round 5). One ds_read_b128 feeds 4 MFMAs. No atomics.
__global__ __launch_bounds__(512, 4) void gemm_exp_stream(const ushort* __restrict__ xb,
                                                          float* __restrict__ rowsumP) {
    __shared__ __align__(16) ushort lB[2][TCOLS * DD];   // 2 x 16 KB

    const int tid  = threadIdx.x;
    const int lane = tid & 63;
    const int wid  = tid >> 6;       // 0..7
    const int frow = lane & 15;
    const int kq   = lane >> 4;

    // XCD locality: 2 XCDs share one 1 MB B-slab (L2-resident).
    const int bid    = blockIdx.x;
    const int cq     = (bid & 7) >> 1;                 // 0..3
    const int rstrip = ((bid >> 3) << 1) | (bid & 1);  // 0..127, bijective
    const int rw = wid >> 2;         // 0..1 -> 64-row band
    const int cw = wid & 3;          // 0..3 -> 16-col slice within tile
    const int R0 = rstrip * BM;
    const int C0 = cq * BCOLS;

    auto stage = [&](int buf, int t) {
        const char* g = (const char*)(xb + (size_t)(C0 + t * TCOLS) * DD);
#pragma unroll
        for (int i = 0; i < 2; ++i) {
            int off = (wid * 2 + i) * 1024;
            __builtin_amdgcn_global_load_lds(
                (const __attribute__((address_space(1))) unsigned int*)(g + off + lane * 16),
                (__attribute__((address_space(3))) unsigned int*)((char*)&lB[buf][0] + off),
                16, 0, 0);
        }
    };

    stage(0, 0);

    // ---- A fragments: 64 rows per wave, full K=128, in registers forever ----
    bf16x8 af[4][4];                 // [m][kk]  (64 VGPR)
#pragma unroll
    for (int m = 0; m < 4; ++m)
#pragma unroll
        for (int kk = 0; kk < 4; ++kk) {
            int ra = R0 + rw * 64 + m * 16 + frow;   // ra & 15 == frow
            int slot = (kk * 4 + kq) ^ frow;
            af[m][kk] = *(const bf16x8*)(xb + (size_t)ra * DD + slot * 8);
        }

    // ---- LDS byte offsets: base (per-lane) + per-kk delta ----
    const int nbase = (cw * 16 + frow) * 256 + ((kq ^ (frow & 3)) << 4);
    int kkoff[4];
#pragma unroll
    for (int kk = 0; kk < 4; ++kk)
        kkoff[kk] = (kk ^ (frow >> 2)) << 6;

    const f32x4 zacc = {0.f, 0.f, 0.f, 0.f};
    float rs[4][4] = {};

    for (int t = 0; t < TILES; ++t) {
        const int cur = t & 1;
        if (t < TILES - 1) {
            stage(cur ^ 1, t + 1);
            asm volatile("s_waitcnt vmcnt(2)" ::: "memory");  // tile t (+A at t=0) landed
        } else {
            asm volatile("s_waitcnt vmcnt(0)" ::: "memory");
        }
        __builtin_amdgcn_s_barrier();

        const char* Bb = (const char*)&lB[cur][0];
        f32x4 acc[4];
#pragma unroll
        for (int kk = 0; kk < 4; ++kk) {
            bf16x8 bfr = *(const bf16x8*)(Bb + nbase + kkoff[kk]);
            __builtin_amdgcn_s_setprio(1);
            if (kk == 0) {
#pragma unroll
                for (int m = 0; m < 4; ++m)
                    acc[m] = __builtin_amdgcn_mfma_f32_16x16x32_bf16(
                        af[m][0], bfr, zacc, 0, 0, 0);
            } else {
#pragma unroll
                for (int m = 0; m < 4; ++m)
                    acc[m] = __builtin_amdgcn_mfma_f32_16x16x32_bf16(
                        af[m][kk], bfr, acc[m], 0, 0, 0);
            }
            __builtin_amdgcn_s_setprio(0);
        }
        __builtin_amdgcn_s_barrier();   // all reads of lB[cur] consumed

        // Register-only epilogue; acc is already the exp2 argument.
#pragma unroll
        for (int m = 0; m < 4; ++m)
#pragma unroll
            for (int j = 0; j < 4; ++j)
                rs[m][j] += __builtin_amdgcn_exp2f(acc[m][j]);
    }

    // ---- cross-lane reduce over the 16 col-lanes ----
#pragma unroll
    for (int m = 0; m < 4; ++m)
#pragma unroll
        for (int j = 0; j < 4; ++j) {
            float s = rs[m][j];
            s += __shfl_xor(s, 1);
            s += __shfl_xor(s, 2);
            s += __shfl_xor(s, 4);
            s += __shfl_xor(s, 8);
            rs[m][j] = s;
        }

    // ---- each colwave writes its own partial slice: no LDS combine ----
    if (frow == 0) {
        const int p = cq * 4 + cw;           // partial slot 0..15
        float* dst = rowsumP + (size_t)p * NN + R0 + rw * 64 + kq * 4;
#pragma unroll
        for (int m = 0; m < 4; ++m) {
            float4 v = {rs[m][0], rs[m][1], rs[m][2], rs[m][3]};
            *(float4*)(dst + m * 16) = v;    // row = R0+rw*64+m*16+kq*4+j
        }
    }
}

// ---------------- Kernel 3a: per-row log, 64-block partial sums ----------------
__global__ void finalize_part(const float* __restrict__ rowsumP,
                              float* __restrict__ partial) {
    const int tid = threadIdx.x;
    const int r = blockIdx.x * 256 + tid;
    float rsum = 0.f;
#pragma unroll
    for (int p = 0; p < 16; ++p)
        rsum += rowsumP[p * NN + r];
    float s = __builtin_amdgcn_logf(rsum) * 0.69314718056f;
#pragma unroll
    for (int o = 1; o < 64; o <<= 1)
        s += __shfl_xor(s, o);
    __shared__ float wsum[4];
    if ((tid & 63) == 0) wsum[tid >> 6] = s;
    __syncthreads();
    if (tid == 0)
        partial[blockIdx.x] = wsum[0] + wsum[1] + wsum[2] + wsum[3];
}

// ---------------- Kernel 3b: final sum -----------------------------------------
__global__ void finalize_sum(const float* __restrict__ partial, float* __restrict__ out) {
    float s = partial[threadIdx.x];   // 64 threads
#pragma unroll
    for (int o = 1; o < 64; o <<= 1)
        s += __shfl_xor(s, o);
    if (threadIdx.x == 0)
        out[0] = s * (1.0f / NN);
}

extern "C" void kernel_launch(void* const* d_in, const int* in_sizes, int n_in,
                              void* d_out, int out_size, void* d_ws, size_t ws_size,
                              hipStream_t stream) {
    const float* x = (const float*)d_in[0];
    float* out = (float*)d_out;

    ushort* xb     = (ushort*)d_ws;                                // 4 MB scaled bf16
    float* rowsumP = (float*)((char*)d_ws + (size_t)NN * DD * 2);  // 16 x 64 KB partials
    float* partial = rowsumP + 16 * NN;                            // 64 floats

    convert_swz<<<(NN * 16) / 256, 256, 0, stream>>>(x, xb);
    gemm_exp_stream<<<NBLOCKS, 512, 0, stream>>>(xb, rowsumP);
    finalize_part<<<64, 256, 0, stream>>>(rowsumP, partial);
    finalize_sum<<<1, 64, 0, stream>>>(partial, out);
}